// Round 1
// baseline (486.595 us; speedup 1.0000x reference)
//
#include <hip/hip_runtime.h>
#include <math.h>

namespace {

constexpr int NQ = 10;
constexpr int NL = 4;
constexpr float PI_F = 3.14159265358979323846f;

// State: per-wave 1024 complex amps. Lane holds amps with idx = (lane<<4)|r.
// Wire w acts on bit p = 9 - w. p<4: in-register pairs; p>=4: lane-bit via shfl_xor.

template<int P>
__device__ __forceinline__ void apply_ry(float (&re)[16], float (&im)[16],
                                         float c, float s, int lane) {
  if constexpr (P < 4) {
    constexpr int bit = 1 << P;
#pragma unroll
    for (int r = 0; r < 16; ++r) {
      if ((r & bit) == 0) {
        int r1 = r | bit;
        float a0r = re[r], a0i = im[r], a1r = re[r1], a1i = im[r1];
        re[r]  = c * a0r - s * a1r;
        im[r]  = c * a0i - s * a1i;
        re[r1] = s * a0r + c * a1r;
        im[r1] = s * a0i + c * a1i;
      }
    }
  } else {
    constexpr int mask = 1 << (P - 4);
    // hi lane (bit set): new = s*other + c*own ; lo lane: new = c*own - s*other
    float ss = ((lane & mask) != 0) ? s : -s;
#pragma unroll
    for (int r = 0; r < 16; ++r) {
      float orr = __shfl_xor(re[r], mask, 64);
      float ori = __shfl_xor(im[r], mask, 64);
      re[r] = c * re[r] + ss * orr;
      im[r] = c * im[r] + ss * ori;
    }
  }
}

template<int P>
__device__ __forceinline__ void apply_rz(float (&re)[16], float (&im)[16],
                                         float c, float s, int lane) {
  // bit0: multiply by (c - i s); bit1: multiply by (c + i s)
  if constexpr (P >= 4) {
    constexpr int mask = 1 << (P - 4);
    float ss = ((lane & mask) != 0) ? s : -s;
#pragma unroll
    for (int r = 0; r < 16; ++r) {
      float nr = c * re[r] - ss * im[r];
      im[r]    = c * im[r] + ss * re[r];
      re[r]    = nr;
    }
  } else {
    constexpr int bit = 1 << P;
#pragma unroll
    for (int r = 0; r < 16; ++r) {
      float ss = (r & bit) ? s : -s;
      float nr = c * re[r] - ss * im[r];
      im[r]    = c * im[r] + ss * re[r];
      re[r]    = nr;
    }
  }
}

template<int PC, int PT>
__device__ __forceinline__ void apply_cnot(float (&re)[16], float (&im)[16], int lane) {
  // new[idx] = (bit PC of idx) ? old[idx ^ (1<<PT)] : old[idx]
  if constexpr (PT >= 4) {
    constexpr int lmask = 1 << (PT - 4);
    if constexpr (PC >= 4) {
      constexpr int cmask = 1 << (PC - 4);
      bool ctrl = (lane & cmask) != 0;
#pragma unroll
      for (int r = 0; r < 16; ++r) {
        float orr = __shfl_xor(re[r], lmask, 64);
        float ori = __shfl_xor(im[r], lmask, 64);
        re[r] = ctrl ? orr : re[r];
        im[r] = ctrl ? ori : im[r];
      }
    } else {
      constexpr int cbit = 1 << PC;
#pragma unroll
      for (int r = 0; r < 16; ++r) {
        if (r & cbit) {  // uniform over lanes; both partners swap -> full exchange
          re[r] = __shfl_xor(re[r], lmask, 64);
          im[r] = __shfl_xor(im[r], lmask, 64);
        }
      }
    }
  } else {
    constexpr int tbit = 1 << PT;
    if constexpr (PC >= 4) {
      constexpr int cmask = 1 << (PC - 4);
      bool ctrl = (lane & cmask) != 0;
#pragma unroll
      for (int r = 0; r < 16; ++r) {
        if ((r & tbit) == 0) {
          int r1 = r | tbit;
          float t0r = re[r], t0i = im[r], t1r = re[r1], t1i = im[r1];
          re[r]  = ctrl ? t1r : t0r;
          im[r]  = ctrl ? t1i : t0i;
          re[r1] = ctrl ? t0r : t1r;
          im[r1] = ctrl ? t0i : t1i;
        }
      }
    } else {
      constexpr int cbit = 1 << PC;
#pragma unroll
      for (int r = 0; r < 16; ++r) {
        if ((r & cbit) && !(r & tbit)) {
          int r1 = r | tbit;
          float t = re[r]; re[r] = re[r1]; re[r1] = t;
          t = im[r]; im[r] = im[r1]; im[r1] = t;
        }
      }
    }
  }
}

__global__ __launch_bounds__(256) void qsim(const float* __restrict__ x,
                                            const float* __restrict__ w,
                                            float* __restrict__ out, int batch) {
  // Shared-weight trig table: (c,s) per (l,i,k), idx = (l*10+i)*3+k
  __shared__ float wt[NL * NQ * 3 * 2];
  int tid = threadIdx.x;
  if (tid < NL * NQ * 3) {
    float cv, sv;
    sincosf(0.5f * w[tid], &sv, &cv);
    wt[2 * tid]     = cv;
    wt[2 * tid + 1] = sv;
  }
  __syncthreads();

  int lane = tid & 63;
  int b = blockIdx.x * 4 + (tid >> 6);
  if (b >= batch) return;

  // Per-element data angles: lanes 0..9 each compute one sincos, broadcast at use.
  float cxv = 1.0f, sxv = 0.0f;
  if (lane < NQ) {
    float th = tanhf(x[b * NQ + lane]) * PI_F;
    sincosf(0.5f * th, &sxv, &cxv);
  }

  float re[16], im[16];
#pragma unroll
  for (int r = 0; r < 16; ++r) { re[r] = 0.0f; im[r] = 0.0f; }
  if (lane == 0) re[0] = 1.0f;

  for (int l = 0; l < NL; ++l) {
    const float* wl = &wt[l * NQ * 6];

#define GATE1(i) { \
    float c = __shfl(cxv, (i), 64), s = __shfl(sxv, (i), 64); \
    apply_ry<9 - (i)>(re, im, c, s, lane); \
    apply_rz<9 - (i)>(re, im, wl[(i) * 6 + 0], wl[(i) * 6 + 1], lane); }
    GATE1(0) GATE1(1) GATE1(2) GATE1(3) GATE1(4)
    GATE1(5) GATE1(6) GATE1(7) GATE1(8) GATE1(9)
#undef GATE1

#define GATE2(i) { \
    apply_ry<9 - (i)>(re, im, wl[(i) * 6 + 2], wl[(i) * 6 + 3], lane); \
    apply_rz<9 - (i)>(re, im, wl[(i) * 6 + 4], wl[(i) * 6 + 5], lane); }
    GATE2(0) GATE2(1) GATE2(2) GATE2(3) GATE2(4)
    GATE2(5) GATE2(6) GATE2(7) GATE2(8) GATE2(9)
#undef GATE2

    // CNOT chain: (c=i,t=i+1) -> (PC=9-i, PT=8-i); final (c=9,t=0) -> (PC=0, PT=9)
    apply_cnot<9, 8>(re, im, lane);
    apply_cnot<8, 7>(re, im, lane);
    apply_cnot<7, 6>(re, im, lane);
    apply_cnot<6, 5>(re, im, lane);
    apply_cnot<5, 4>(re, im, lane);
    apply_cnot<4, 3>(re, im, lane);
    apply_cnot<3, 2>(re, im, lane);
    apply_cnot<2, 1>(re, im, lane);
    apply_cnot<1, 0>(re, im, lane);
    apply_cnot<0, 9>(re, im, lane);
  }

  // Measurement: out[b][q] = sum_idx prob[idx] * (bit(9-q) ? -1 : +1)
  float prob[16];
  float total = 0.0f;
#pragma unroll
  for (int r = 0; r < 16; ++r) {
    prob[r] = re[r] * re[r] + im[r] * im[r];
    total += prob[r];
  }
  float part[10];
#pragma unroll
  for (int p = 0; p < 4; ++p) {
    float acc = 0.0f;
#pragma unroll
    for (int r = 0; r < 16; ++r)
      acc += (r & (1 << p)) ? -prob[r] : prob[r];
    part[p] = acc;
  }
#pragma unroll
  for (int p = 4; p < 10; ++p)
    part[p] = (lane & (1 << (p - 4))) ? -total : total;

#pragma unroll
  for (int p = 0; p < 10; ++p) {
#pragma unroll
    for (int m = 1; m < 64; m <<= 1)
      part[p] += __shfl_xor(part[p], m, 64);
  }

  if (lane == 0) {
#pragma unroll
    for (int q = 0; q < NQ; ++q)
      out[b * NQ + q] = part[9 - q];
  }
}

}  // namespace

extern "C" void kernel_launch(void* const* d_in, const int* in_sizes, int n_in,
                              void* d_out, int out_size, void* d_ws, size_t ws_size,
                              hipStream_t stream) {
  const float* x = (const float*)d_in[0];
  const float* w = (const float*)d_in[1];
  float* out = (float*)d_out;
  int batch = in_sizes[0] / NQ;
  int blocks = (batch + 3) / 4;  // 4 waves/block, 1 batch element per wave
  qsim<<<blocks, 256, 0, stream>>>(x, w, out, batch);
}

// Round 2
// 338.421 us; speedup vs baseline: 1.4378x; 1.4378x over previous
//
#include <hip/hip_runtime.h>
#include <math.h>

namespace {

constexpr int NQ = 10;
constexpr int NL = 4;
constexpr float PI_F = 3.14159265358979323846f;

// State: per-wave 1024 complex amps. Lane holds amps with idx = (lane<<4)|r.
// Wire w acts on bit p = 9 - w. p<4: in-register pairs; p>=4: lane-bit via shfl_xor.
//
// Fusion: per (layer, wire) the reference applies RY(data)*RZ(w0)*RY(w1)*RZ(w2)
// (gates on different wires commute, so the per-wire subsequence is contiguous).
// W = RZ(w2)*RY(w1)*RZ(w0) is batch-shared, precomputed into LDS; per element
// U = W * RY(a) is ONE complex 2x2 gate -> 2x fewer VALU ops and 2x fewer
// lane exchanges than the unfused form.

template<int P>
__device__ __forceinline__ void apply_u(float (&re)[16], float (&im)[16],
                                        float u00r, float u00i, float u01r, float u01i,
                                        float u10r, float u10i, float u11r, float u11i,
                                        int lane) {
  if constexpr (P < 4) {
    constexpr int bit = 1 << P;
#pragma unroll
    for (int r = 0; r < 16; ++r) {
      if ((r & bit) == 0) {
        int r1 = r | bit;
        float a0r = re[r], a0i = im[r], a1r = re[r1], a1i = im[r1];
        re[r]  = u00r * a0r - u00i * a0i + u01r * a1r - u01i * a1i;
        im[r]  = u00r * a0i + u00i * a0r + u01r * a1i + u01i * a1r;
        re[r1] = u10r * a0r - u10i * a0i + u11r * a1r - u11i * a1i;
        im[r1] = u10r * a0i + u10i * a0r + u11r * a1i + u11i * a1r;
      }
    }
  } else {
    constexpr int mask = 1 << (P - 4);
    bool hi = (lane & mask) != 0;
    // own-coef = hi ? u11 : u00 ; partner-coef = hi ? u10 : u01
    float cAr = hi ? u11r : u00r, cAi = hi ? u11i : u00i;
    float cBr = hi ? u10r : u01r, cBi = hi ? u10i : u01i;
#pragma unroll
    for (int r = 0; r < 16; ++r) {
      float pr = __shfl_xor(re[r], mask, 64);
      float pi = __shfl_xor(im[r], mask, 64);
      float orr = re[r], oi = im[r];
      re[r] = cAr * orr - cAi * oi + cBr * pr - cBi * pi;
      im[r] = cAr * oi + cAi * orr + cBr * pi + cBi * pr;
    }
  }
}

__global__ __launch_bounds__(256) void qsim(const float* __restrict__ x,
                                            const float* __restrict__ w,
                                            float* __restrict__ out, int batch) {
  // Batch-shared fused weight matrices W = RZ(w2)*RY(w1)*RZ(w0), one complex
  // 2x2 per (layer, wire): [w00, w01 | w10, w11] as two float4.
  __shared__ float4 wmat[NL * NQ * 2];
  int tid = threadIdx.x;
  if (tid < NL * NQ) {
    const float* wp = &w[tid * 3];
    float t0 = 0.5f * wp[0], t1 = 0.5f * wp[1], t2 = 0.5f * wp[2];
    float c1, s1; sincosf(t1, &s1, &c1);
    float cA, sA; sincosf(t0 + t2, &sA, &cA);
    float cB, sB; sincosf(t0 - t2, &sB, &cB);
    // w00 = c1*e^{-iA}; w01 = -s1*e^{+iB}; w10 = s1*e^{-iB}; w11 = c1*e^{+iA}
    wmat[tid * 2]     = make_float4(c1 * cA, -c1 * sA, -s1 * cB, -s1 * sB);
    wmat[tid * 2 + 1] = make_float4(s1 * cB, -s1 * sB,  c1 * cA,  c1 * sA);
  }
  __syncthreads();

  int lane = tid & 63;
  int b = blockIdx.x * 4 + (tid >> 6);
  if (b >= batch) return;

  // Per-element data angles: lanes 0..9 each compute one sincos, broadcast at use.
  float cxv = 1.0f, sxv = 0.0f;
  if (lane < NQ) {
    float th = tanhf(x[b * NQ + lane]) * PI_F;
    sincosf(0.5f * th, &sxv, &cxv);
  }

  // Composed lane-permutation for the 5 lane-lane CNOTs (state bits (9,8)..(5,4)
  // = lane bits (5,4)..(1,0), applied in that order). new[l] = old[srcl].
  int srcl;
  {
    int t = lane;
    t ^= (t >> 1) & 1;          // last gate  C(1,0)
    t ^= ((t >> 2) & 1) << 1;   //            C(2,1)
    t ^= ((t >> 3) & 1) << 2;   //            C(3,2)
    t ^= ((t >> 4) & 1) << 3;   //            C(4,3)
    t ^= ((t >> 5) & 1) << 4;   // first gate C(5,4)
    srcl = t;
  }

  float re[16], im[16];
#pragma unroll
  for (int r = 0; r < 16; ++r) { re[r] = 0.0f; im[r] = 0.0f; }
  if (lane == 0) re[0] = 1.0f;

  for (int l = 0; l < NL; ++l) {
#define FUSED(i) { \
    float4 wa = wmat[(l * NQ + (i)) * 2], wb = wmat[(l * NQ + (i)) * 2 + 1]; \
    float ca = __shfl(cxv, (i), 64), sa = __shfl(sxv, (i), 64); \
    float u00r = ca * wa.x + sa * wa.z, u00i = ca * wa.y + sa * wa.w; \
    float u01r = ca * wa.z - sa * wa.x, u01i = ca * wa.w - sa * wa.y; \
    float u10r = ca * wb.x + sa * wb.z, u10i = ca * wb.y + sa * wb.w; \
    float u11r = ca * wb.z - sa * wb.x, u11i = ca * wb.w - sa * wb.y; \
    apply_u<9 - (i)>(re, im, u00r, u00i, u01r, u01i, u10r, u10i, u11r, u11i, lane); }
    FUSED(0) FUSED(1) FUSED(2) FUSED(3) FUSED(4)
    FUSED(5) FUSED(6) FUSED(7) FUSED(8) FUSED(9)
#undef FUSED

    // --- CNOT chain: (9,8)(8,7)(7,6)(6,5)(5,4) | (4,3) | (3,2)(2,1)(1,0) | (0,9)
    // 1) five lane-lane CNOTs as ONE composed bpermute
#pragma unroll
    for (int r = 0; r < 16; ++r) {
      re[r] = __shfl(re[r], srcl, 64);
      im[r] = __shfl(im[r], srcl, 64);
    }
    // 2) (4,3): ctrl = lane bit 0, target = reg bit 3
    {
      bool ctrl = (lane & 1) != 0;
#pragma unroll
      for (int r = 0; r < 8; ++r) {
        int r1 = r | 8;
        float t0r = re[r], t0i = im[r], t1r = re[r1], t1i = im[r1];
        re[r]  = ctrl ? t1r : t0r;  im[r]  = ctrl ? t1i : t0i;
        re[r1] = ctrl ? t0r : t1r;  im[r1] = ctrl ? t0i : t1i;
      }
    }
    // 3) (3,2)(2,1)(1,0): pure compile-time register permutation
    {
      float tr[16], ti[16];
#pragma unroll
      for (int r = 0; r < 16; ++r) { tr[r] = re[r]; ti[r] = im[r]; }
#pragma unroll
      for (int r = 0; r < 16; ++r) {
        int s = r ^ ((r >> 1) & 1);     // last gate  C(1,0)
        s ^= ((s >> 2) & 1) << 1;       //            C(2,1)
        s ^= ((s >> 3) & 1) << 2;       // first gate C(3,2)
        re[r] = tr[s]; im[r] = ti[s];
      }
    }
    // 4) (0,9): ctrl = reg bit 0, target = lane bit 5 -> full exchange on odd r
#pragma unroll
    for (int r = 1; r < 16; r += 2) {
      re[r] = __shfl_xor(re[r], 32, 64);
      im[r] = __shfl_xor(im[r], 32, 64);
    }
  }

  // Measurement: out[b][q] = sum_idx prob[idx] * (bit(9-q) ? -1 : +1)
  float prob[16];
  float total = 0.0f;
#pragma unroll
  for (int r = 0; r < 16; ++r) {
    prob[r] = re[r] * re[r] + im[r] * im[r];
    total += prob[r];
  }
  float part[10];
#pragma unroll
  for (int p = 0; p < 4; ++p) {
    float acc = 0.0f;
#pragma unroll
    for (int r = 0; r < 16; ++r)
      acc += (r & (1 << p)) ? -prob[r] : prob[r];
    part[p] = acc;
  }
#pragma unroll
  for (int p = 4; p < 10; ++p)
    part[p] = (lane & (1 << (p - 4))) ? -total : total;

#pragma unroll
  for (int p = 0; p < 10; ++p) {
#pragma unroll
    for (int m = 1; m < 64; m <<= 1)
      part[p] += __shfl_xor(part[p], m, 64);
  }

  if (lane == 0) {
#pragma unroll
    for (int q = 0; q < NQ; ++q)
      out[b * NQ + q] = part[9 - q];
  }
}

}  // namespace

extern "C" void kernel_launch(void* const* d_in, const int* in_sizes, int n_in,
                              void* d_out, int out_size, void* d_ws, size_t ws_size,
                              hipStream_t stream) {
  const float* x = (const float*)d_in[0];
  const float* w = (const float*)d_in[1];
  float* out = (float*)d_out;
  int batch = in_sizes[0] / NQ;
  int blocks = (batch + 3) / 4;  // 4 waves/block, 1 batch element per wave
  qsim<<<blocks, 256, 0, stream>>>(x, w, out, batch);
}